// Round 18
// baseline (628.610 us; speedup 1.0000x reference)
//
#include <hip/hip_runtime.h>

// EntityLinker fused edge-MLP for MI355X (gfx950).
// Round 30: M-split waves — wave-private rows end the convoy.
//   R28 measured: staging-phase+2-barrier removal = 327.4 -> 310.7us (-5%),
//   but VALUBusy 24 -> 44.6%: the N-split made every wave recompute comb
//   for ALL 64 rows (4x redundant). Fix: split layer-1/2 by M. Wave wv owns
//   rows wv*16..wv*16+15, all cols. Then: gather (t>>2) is already
//   wave-aligned; layer-1 A-reads, comb (1/4 the VALU), x1 write, layer-2,
//   x2 write (stride 268 -> rows never cross waves), and Phase-F row reads
//   are ALL wave-private. Cross-wave sharing survives only at sW3 (A->F).
//   Barriers 5 -> 2 (A->B kept as a guard this round; post-E covers sW3).
//   Waves slide freely through B..E -> stall overlap across 16 independent
//   streams/CU. Weight fragments now read by all 4 waves (L1-served,
//   16KB/ks << 32KB L1). Accumulation order per output unchanged (k-major)
//   -> bit-identical to R28. prep kernels unchanged.
//   Predict: dur 310 -> 270-290; VALUBusy -> ~32; VGPR watch <=64.
//   Keeps: 4 blocks/CU, bf16 node cache, fragment-major packed weights,
//   vectorized sW3 phase-F.

#define H 128

typedef __bf16 bf16x8 __attribute__((ext_vector_type(8)));
typedef float f32x4 __attribute__((ext_vector_type(4)));

__device__ __forceinline__ unsigned short f2bf(float f) {
    unsigned u = __builtin_bit_cast(unsigned, f);
    u += 0x7FFFu + ((u >> 16) & 1u);   // RNE
    return (unsigned short)(u >> 16);
}
__device__ __forceinline__ float bfhi(unsigned u) {
    return __builtin_bit_cast(float, u & 0xffff0000u);
}
__device__ __forceinline__ float bflo(unsigned u) {
    return __builtin_bit_cast(float, u << 16);
}
__device__ __forceinline__ unsigned pk2(float r0, float r1) {
    unsigned u0 = __builtin_bit_cast(unsigned, r0) + 0x8000u;
    unsigned u1 = __builtin_bit_cast(unsigned, r1) + 0x8000u;
    return __builtin_amdgcn_perm(u1, u0, 0x07060302u);
}
__device__ __forceinline__ unsigned comb(unsigned ua, unsigned ub, bool isdiff) {
    float a0 = bflo(ua), a1 = bfhi(ua);
    float b0 = bflo(ub), b1 = bfhi(ub);
    float r0 = isdiff ? fabsf(a0 - b0) : a0 * b0;
    float r1 = isdiff ? fabsf(a1 - b1) : a1 * b1;
    return pk2(r0, r1);
}
__device__ __forceinline__ unsigned short cvt1(float v) {
    unsigned u = __builtin_bit_cast(unsigned, v) + 0x8000u;
    return (unsigned short)(u >> 16);
}

__global__ void prep_node(const float* __restrict__ node, unsigned short* __restrict__ nbf) {
    int idx = blockIdx.x * 256 + threadIdx.x;      // N*H/4 threads, 4 elems each
    const f32x4* p = (const f32x4*)(node) + idx;
    f32x4 v = *p;
    ushort4 w;
    w.x = f2bf(v.x); w.y = f2bf(v.y); w.z = f2bf(v.z); w.w = f2bf(v.w);
    *(ushort4*)(nbf + idx * 4) = w;
}

// Fragment-major pack of W1 [512][256] (in,out):
//   W1P[o], o = (g_nt*16 + ks)*512 + lane*8 + j
//   row = g_nt*16 + (lane&15), k = ks*32 + (lane>>4)*8 + j
__global__ void prep_w1(const float* __restrict__ W1, unsigned short* __restrict__ W1P) {
    int o = blockIdx.x * 256 + threadIdx.x;        // 131072
    int chunk = o >> 9;
    int g_nt = chunk >> 4;
    int ks = chunk & 15;
    int r = o & 511;
    int lane = r >> 3;
    int j = r & 7;
    int row = g_nt * 16 + (lane & 15);
    int k = ks * 32 + (lane >> 4) * 8 + j;
    W1P[o] = f2bf(W1[k * 256 + row]);
}

// Fragment-major pack of W2 [256][128]:
//   W2P[o], o = (g_nt*8 + ks)*512 + lane*8 + j
__global__ void prep_w2(const float* __restrict__ W2, unsigned short* __restrict__ W2P) {
    int o = blockIdx.x * 256 + threadIdx.x;        // 32768
    int chunk = o >> 9;
    int g_nt = chunk >> 3;
    int ks = chunk & 7;
    int r = o & 511;
    int lane = r >> 3;
    int j = r & 7;
    int row = g_nt * 16 + (lane & 15);
    int k = ks * 32 + (lane >> 4) * 8 + j;
    W2P[o] = f2bf(W2[k * 128 + row]);
}

__launch_bounds__(256, 4)
__global__ void fused_mlp(const unsigned short* __restrict__ nbf,   // [N][128] bf16
                          const int* __restrict__ src,
                          const int* __restrict__ dst,
                          const unsigned short* __restrict__ W1P,  // packed
                          const float* __restrict__ b1,
                          const unsigned short* __restrict__ W2P,  // packed
                          const float* __restrict__ b2,
                          const float* __restrict__ W3,            // [128][2] f32
                          const float* __restrict__ b3,
                          float* __restrict__ out,                 // [E][2] f32
                          int E) {
    // sH: [64][268] bf16. Region P (cols 0..127): hi. Region Q (136..263): hj.
    // Overlays (all at stride 268, wave-private rows): x1 cols 0..255,
    // then x2 cols 0..127.
    __shared__ __align__(16) unsigned short sH[64 * 268];    // 34304 B
    __shared__ __align__(16) float sW3[256];                 // [c][128]

    const int t = threadIdx.x;
    const int e0 = blockIdx.x * 64;

    const int lane = t & 63;
    const int wv = t >> 6;
    const int quad = lane >> 4;
    const int lrow = lane & 15;

    // Weight bases: every wave streams ALL N-slices (M-split), so no wv term.
    const unsigned short* w1b = W1P + lane * 8;
    const unsigned short* w2b = W2P + lane * 8;

    // ---------------- Phase A: gather hi/hj (bf16) -> LDS, wave-private rows ----
    // t>>2 in [wv*16, wv*16+15]: each wave writes exactly the rows it consumes.
    {
        int r = t >> 2;            // edge row 0..63
        int q = t & 3;             // 32-col quarter (64 B = one cache line)
        int e = e0 + r;
        int ec = e < E ? e : (E - 1);
        const unsigned short* hi = nbf + (long)src[ec] * H + q * 32;
        const unsigned short* hj = nbf + (long)dst[ec] * H + q * 32;
        unsigned short* rowp = sH + r * 268 + q * 32;
#pragma unroll
        for (int b = 0; b < 4; b++) {
            uint4 a = *(const uint4*)(hi + b * 8);
            uint4 c = *(const uint4*)(hj + b * 8);
            *(uint4*)(rowp + b * 8)       = a;
            *(uint4*)(rowp + 136 + b * 8) = c;
        }
        sW3[(t & 1) * 128 + (t >> 1)] = W3[t];   // [k][c] -> [c][k]
    }
    __syncthreads();               // guard: cross-lane gather->read within wave

    // ---------------- Phase B: layer 1 (wave rows x N=256, K=512) ---------------
    f32x4 acc[16];
#pragma unroll
    for (int nt = 0; nt < 16; nt++) acc[nt] = (f32x4){0.f, 0.f, 0.f, 0.f};

    const int aoff = (wv * 16 + lrow) * 268 + quad * 8;

    // K-half 1: k 0..255 (A = hi | hj, as stored), own rows only.
#pragma unroll 1
    for (int ks = 0; ks < 8; ks++) {
        const int ao = (ks < 4) ? ks * 32 : 136 + (ks - 4) * 32;
        bf16x8 av = *(const bf16x8*)(sH + aoff + ao);
#pragma unroll
        for (int nt = 0; nt < 16; nt++) {
            bf16x8 bv = *(const bf16x8*)(w1b + nt * 8192 + ks * 512);
            acc[nt] = __builtin_amdgcn_mfma_f32_16x16x32_bf16(av, bv, acc[nt], 0, 0, 0);
        }
    }

    // K-half 2a: k 256..383 (A = diff), comb on the fly from own-row hi/hj.
#pragma unroll 1
    for (int ks = 0; ks < 4; ks++) {
        uint4 hu = *(const uint4*)(sH + aoff + ks * 32);
        uint4 ju = *(const uint4*)(sH + aoff + 136 + ks * 32);
        uint4 cv;
        cv.x = comb(hu.x, ju.x, true);  cv.y = comb(hu.y, ju.y, true);
        cv.z = comb(hu.z, ju.z, true);  cv.w = comb(hu.w, ju.w, true);
        bf16x8 av = __builtin_bit_cast(bf16x8, cv);
#pragma unroll
        for (int nt = 0; nt < 16; nt++) {
            bf16x8 bv = *(const bf16x8*)(w1b + nt * 8192 + (ks + 8) * 512);
            acc[nt] = __builtin_amdgcn_mfma_f32_16x16x32_bf16(av, bv, acc[nt], 0, 0, 0);
        }
    }

    // K-half 2b: k 384..511 (A = prod).
#pragma unroll 1
    for (int ks = 0; ks < 4; ks++) {
        uint4 hu = *(const uint4*)(sH + aoff + ks * 32);
        uint4 ju = *(const uint4*)(sH + aoff + 136 + ks * 32);
        uint4 cv;
        cv.x = comb(hu.x, ju.x, false); cv.y = comb(hu.y, ju.y, false);
        cv.z = comb(hu.z, ju.z, false); cv.w = comb(hu.w, ju.w, false);
        bf16x8 av = __builtin_bit_cast(bf16x8, cv);
#pragma unroll
        for (int nt = 0; nt < 16; nt++) {
            bf16x8 bv = *(const bf16x8*)(w1b + nt * 8192 + (ks + 12) * 512);
            acc[nt] = __builtin_amdgcn_mfma_f32_16x16x32_bf16(av, bv, acc[nt], 0, 0, 0);
        }
    }

    // ---------------- Phase C: relu+bias -> x1 bf16, own rows — NO barriers -----
    // Overwrites hi/hj of OWN rows only; K-loop reads completed in program order.
    unsigned short* sx1 = sH;      // stride 268, cols 0..255
#pragma unroll
    for (int nt = 0; nt < 16; nt++) {
        float bb = b1[nt * 16 + lrow];
#pragma unroll
        for (int i = 0; i < 4; i++) {
            int row = wv * 16 + quad * 4 + i;    // C/D: row = quad*4 + reg
            float v = acc[nt][i] + bb;
            v = v > 0.f ? v : 0.f;
            sx1[row * 268 + nt * 16 + lrow] = cvt1(v);
        }
    }

    // ---------------- Phase D: layer 2 (wave rows x N=128, K=256) ---------------
    f32x4 acc2[8];
#pragma unroll
    for (int nt = 0; nt < 8; nt++) acc2[nt] = (f32x4){0.f, 0.f, 0.f, 0.f};

#pragma unroll 1
    for (int ks = 0; ks < 8; ks++) {
        bf16x8 av2 = *(const bf16x8*)(sx1 + aoff + ks * 32);
#pragma unroll
        for (int nt = 0; nt < 8; nt++) {
            bf16x8 bv2 = *(const bf16x8*)(w2b + nt * 4096 + ks * 512);
            acc2[nt] = __builtin_amdgcn_mfma_f32_16x16x32_bf16(av2, bv2, acc2[nt], 0, 0, 0);
        }
    }

    // ---------------- Phase E: relu+bias -> x2 bf16, own rows, stride 268 -------
    unsigned short* sx2 = sH;      // stride 268, cols 0..127 (wave-private rows)
#pragma unroll
    for (int nt = 0; nt < 8; nt++) {
        float bb = b2[nt * 16 + lrow];
#pragma unroll
        for (int i = 0; i < 4; i++) {
            int row = wv * 16 + quad * 4 + i;
            float v = acc2[nt][i] + bb;
            v = v > 0.f ? v : 0.f;
            sx2[row * 268 + nt * 16 + lrow] = cvt1(v);
        }
    }
    __syncthreads();               // x2 rows + sW3 visible for Phase F

    // ---------------- Phase F: layer 3 (N=2), half-dots + shfl ----------------
    {
        int r = t >> 2;            // edge row 0..63 (own-wave rows)
        int c = t & 1;             // class
        int h = (t >> 1) & 1;      // K-half
        const unsigned short* xr = sH + r * 268 + h * 64;
        const float* w3c = sW3 + c * 128 + h * 64;
        float s = 0.f;
#pragma unroll
        for (int j = 0; j < 8; j++) {
            uint4 v = *(const uint4*)(xr + j * 8);
            f32x4 w0 = *(const f32x4*)(w3c + j * 8);
            f32x4 w1 = *(const f32x4*)(w3c + j * 8 + 4);
            s += bflo(v.x) * w0[0] + bfhi(v.x) * w0[1]
               + bflo(v.y) * w0[2] + bfhi(v.y) * w0[3]
               + bflo(v.z) * w1[0] + bfhi(v.z) * w1[1]
               + bflo(v.w) * w1[2] + bfhi(v.w) * w1[3];
        }
        s += __shfl_xor(s, 2);     // combine K-halves
        int e = e0 + r;
        if (h == 0 && e < E) out[e * 2 + c] = s + b3[c];
    }
}

extern "C" void kernel_launch(void* const* d_in, const int* in_sizes, int n_in,
                              void* d_out, int out_size, void* d_ws, size_t ws_size,
                              hipStream_t stream) {
    const float* node = (const float*)d_in[0];
    const int* src    = (const int*)d_in[1];
    const int* dst    = (const int*)d_in[2];
    const float* W1   = (const float*)d_in[3];
    const float* b1   = (const float*)d_in[4];
    const float* W2   = (const float*)d_in[5];
    const float* b2   = (const float*)d_in[6];
    const float* W3   = (const float*)d_in[7];
    const float* b3   = (const float*)d_in[8];
    float* out = (float*)d_out;
    const int NN = in_sizes[0] / H;                    // 50000 nodes
    const int E = in_sizes[1];

    unsigned short* W1P = (unsigned short*)d_ws;       // packed W1, 256 KiB
    unsigned short* W2P = W1P + 512 * 256;             // packed W2, 64 KiB
    unsigned short* NBF = W2P + 256 * 128;             // [N][128] bf16, 12.8 MB

    hipLaunchKernelGGL(prep_node, dim3((NN * H / 4 + 255) / 256), dim3(256), 0, stream, node, NBF);
    hipLaunchKernelGGL(prep_w1, dim3(512), dim3(256), 0, stream, W1, W1P);
    hipLaunchKernelGGL(prep_w2, dim3(128), dim3(256), 0, stream, W2, W2P);
    const int nblk = (E + 63) / 64;
    hipLaunchKernelGGL(fused_mlp, dim3(nblk), dim3(256), 0, stream,
                       NBF, src, dst, W1P, b1, W2P, b2, W3, b3, out, E);
}

// Round 19
// 349.066 us; speedup vs baseline: 1.8008x; 1.8008x over previous
//
#include <hip/hip_runtime.h>

// EntityLinker fused edge-MLP for MI355X (gfx950).
// Round 31: revert to R28 (best measured, 310.7us) + fused K-half-2.
//   R30 post-mortem: M-split REGRESSED 310->557us. Cause: every wave
//   streamed ALL 320KB of weights (4x weight traffic, w1b lost its wv
//   term) -> inner loop load-latency-bound (MfmaUtil 23->12, VALU
//   44.6->17.7). N-split's per-wave weight privacy is load-bearing;
//   interior barriers are structurally required (x1's K-dim crosses
//   wave column ownership). R28 stands.
//   This round's trim (R28 counters: VALU demand ~2.5x MFMA; comb
//   ~1440 instr/wave dominates): fuse K-half-2a/2b into one loop --
//   load hu/ju ONCE per (ks,mt) (K2 LDS reads halve), share the 4
//   bf16 extracts between diff and prod, pack via v_cvt_pk_bf16_f32
//   (1 instr vs pk2's 3; HW-verified inline asm). comb 18 -> 12 VALU
//   per component (-380 instr/wave). avd[4]+avp[4] = 32 VGPR held;
//   bv loads stay hoisted per (ks,nt) -- same weight-load count.
//   Accum order interleaves k-slices (8,12),(9,13).. (f32 reorder,
//   negligible); cvt_pk RNE vs +0x8000 is <=1ulp bf16.
//   Predict: dur 298-306; VALUBusy ~40; VGPR <=64 (spill = failure
//   mode -> revert to split loops); absmax ~0.015-0.03.
//   Keeps (R28): 4 blocks/CU, N-split waves, bf16 node cache,
//   fragment-major packed weights, on-the-fly comb (no staging
//   phase, 5 barriers), vectorized sW3 Phase F.

#define H 128

typedef __bf16 bf16x8 __attribute__((ext_vector_type(8)));
typedef float f32x4 __attribute__((ext_vector_type(4)));

__device__ __forceinline__ unsigned short f2bf(float f) {
    unsigned u = __builtin_bit_cast(unsigned, f);
    u += 0x7FFFu + ((u >> 16) & 1u);   // RNE
    return (unsigned short)(u >> 16);
}
__device__ __forceinline__ float bfhi(unsigned u) {
    return __builtin_bit_cast(float, u & 0xffff0000u);
}
__device__ __forceinline__ float bflo(unsigned u) {
    return __builtin_bit_cast(float, u << 16);
}
// Shared-extract diff+prod: 4 extracts + 2 sub + 2 abs + 2 mul + 2 cvt_pk
// (vs 2x separate comb = 18 ops). v_cvt_pk_bf16_f32: lo=bf16(src0),
// hi=bf16(src1), RNE.
__device__ __forceinline__ void comb2(unsigned ua, unsigned ub,
                                      unsigned& dd, unsigned& pp) {
    float a0 = bflo(ua), a1 = bfhi(ua);
    float b0 = bflo(ub), b1 = bfhi(ub);
    float d0 = fabsf(a0 - b0), d1 = fabsf(a1 - b1);
    float p0 = a0 * b0,        p1 = a1 * b1;
    unsigned rd, rp;
    asm("v_cvt_pk_bf16_f32 %0, %1, %2" : "=v"(rd) : "v"(d0), "v"(d1));
    asm("v_cvt_pk_bf16_f32 %0, %1, %2" : "=v"(rp) : "v"(p0), "v"(p1));
    dd = rd; pp = rp;
}
__device__ __forceinline__ unsigned short cvt1(float v) {
    unsigned u = __builtin_bit_cast(unsigned, v) + 0x8000u;
    return (unsigned short)(u >> 16);
}

__global__ void prep_node(const float* __restrict__ node, unsigned short* __restrict__ nbf) {
    int idx = blockIdx.x * 256 + threadIdx.x;      // N*H/4 threads, 4 elems each
    const f32x4* p = (const f32x4*)(node) + idx;
    f32x4 v = *p;
    ushort4 w;
    w.x = f2bf(v.x); w.y = f2bf(v.y); w.z = f2bf(v.z); w.w = f2bf(v.w);
    *(ushort4*)(nbf + idx * 4) = w;
}

// Fragment-major pack of W1 [512][256] (in,out):
//   W1P[o], o = (g_nt*16 + ks)*512 + lane*8 + j
//   row = g_nt*16 + (lane&15), k = ks*32 + (lane>>4)*8 + j
__global__ void prep_w1(const float* __restrict__ W1, unsigned short* __restrict__ W1P) {
    int o = blockIdx.x * 256 + threadIdx.x;        // 131072
    int chunk = o >> 9;
    int g_nt = chunk >> 4;
    int ks = chunk & 15;
    int r = o & 511;
    int lane = r >> 3;
    int j = r & 7;
    int row = g_nt * 16 + (lane & 15);
    int k = ks * 32 + (lane >> 4) * 8 + j;
    W1P[o] = f2bf(W1[k * 256 + row]);
}

// Fragment-major pack of W2 [256][128]:
//   W2P[o], o = (g_nt*8 + ks)*512 + lane*8 + j
__global__ void prep_w2(const float* __restrict__ W2, unsigned short* __restrict__ W2P) {
    int o = blockIdx.x * 256 + threadIdx.x;        // 32768
    int chunk = o >> 9;
    int g_nt = chunk >> 3;
    int ks = chunk & 7;
    int r = o & 511;
    int lane = r >> 3;
    int j = r & 7;
    int row = g_nt * 16 + (lane & 15);
    int k = ks * 32 + (lane >> 4) * 8 + j;
    W2P[o] = f2bf(W2[k * 128 + row]);
}

__launch_bounds__(256, 4)
__global__ void fused_mlp(const unsigned short* __restrict__ nbf,   // [N][128] bf16
                          const int* __restrict__ src,
                          const int* __restrict__ dst,
                          const unsigned short* __restrict__ W1P,  // packed
                          const float* __restrict__ b1,
                          const unsigned short* __restrict__ W2P,  // packed
                          const float* __restrict__ b2,
                          const float* __restrict__ W3,            // [128][2] f32
                          const float* __restrict__ b3,
                          float* __restrict__ out,                 // [E][2] f32
                          int E) {
    // sH: [64][268] bf16. Region P (cols 0..127): hi (never overwritten
    //     during layer 1). Region Q (cols 136..263): hj.
    // Overlays: x1 [64][268] cols 0..255 (after barrier); x2 [64][140].
    __shared__ __align__(16) unsigned short sH[64 * 268];    // 34304 B
    __shared__ __align__(16) float sW3[256];                 // [c][128]

    const int t = threadIdx.x;
    const int e0 = blockIdx.x * 64;

    const int lane = t & 63;
    const int wv = t >> 6;
    const int quad = lane >> 4;
    const int lrow = lane & 15;
    const int nb = wv * 64;        // layer-1 N-slice
    const int nb2 = wv * 32;       // layer-2 N-slice

    // Weight stream bases (N-split: each wave streams ONLY its N-slices).
    const unsigned short* w1b = W1P + wv * 32768 + lane * 8;   // wv*4*16*512
    const unsigned short* w2b = W2P + wv * 8192 + lane * 8;    // wv*2*8*512

    // ---------------- Phase A: gather hi/hj (bf16) -> LDS, line-granular --------
    {
        int r = t >> 2;            // edge row 0..63
        int q = t & 3;             // 32-col quarter (64 B = one cache line)
        int e = e0 + r;
        int ec = e < E ? e : (E - 1);
        const unsigned short* hi = nbf + (long)src[ec] * H + q * 32;
        const unsigned short* hj = nbf + (long)dst[ec] * H + q * 32;
        unsigned short* rowp = sH + r * 268 + q * 32;
#pragma unroll
        for (int b = 0; b < 4; b++) {
            uint4 a = *(const uint4*)(hi + b * 8);
            uint4 c = *(const uint4*)(hj + b * 8);
            *(uint4*)(rowp + b * 8)       = a;
            *(uint4*)(rowp + 136 + b * 8) = c;
        }
        sW3[(t & 1) * 128 + (t >> 1)] = W3[t];   // [k][c] -> [c][k]
    }
    __syncthreads();               // hi/hj visible

    // ---------------- Phase B: layer 1 (M=64, N=256, K=512), barrier-free -------
    f32x4 acc[4][4];
#pragma unroll
    for (int mt = 0; mt < 4; mt++)
#pragma unroll
        for (int nt = 0; nt < 4; nt++)
            acc[mt][nt] = (f32x4){0.f, 0.f, 0.f, 0.f};

    int aoff[4];
#pragma unroll
    for (int mt = 0; mt < 4; mt++) aoff[mt] = (mt * 16 + lrow) * 268 + quad * 8;

    // K-half 1: k 0..255  (A = hi | hj, as stored)
#pragma unroll 1
    for (int ks = 0; ks < 8; ks++) {
        const int ao = (ks < 4) ? ks * 32 : 136 + (ks - 4) * 32;
        bf16x8 bv[4], av[4];
#pragma unroll
        for (int nt = 0; nt < 4; nt++) bv[nt] = *(const bf16x8*)(w1b + nt * 8192 + ks * 512);
#pragma unroll
        for (int mt = 0; mt < 4; mt++) av[mt] = *(const bf16x8*)(sH + aoff[mt] + ao);
#pragma unroll
        for (int mt = 0; mt < 4; mt++)
#pragma unroll
            for (int nt = 0; nt < 4; nt++)
                acc[mt][nt] = __builtin_amdgcn_mfma_f32_16x16x32_bf16(av[mt], bv[nt], acc[mt][nt], 0, 0, 0);
    }

    // K-half 2 (fused): per ks, build diff (k-slice ks+8) AND prod (ks+12)
    // A-fragments from ONE hu/ju read with shared extracts, then MFMA both.
#pragma unroll 1
    for (int ks = 0; ks < 4; ks++) {
        bf16x8 avd[4], avp[4];
#pragma unroll
        for (int mt = 0; mt < 4; mt++) {
            uint4 hu = *(const uint4*)(sH + aoff[mt] + ks * 32);
            uint4 ju = *(const uint4*)(sH + aoff[mt] + 136 + ks * 32);
            uint4 cd, cp;
            comb2(hu.x, ju.x, cd.x, cp.x);
            comb2(hu.y, ju.y, cd.y, cp.y);
            comb2(hu.z, ju.z, cd.z, cp.z);
            comb2(hu.w, ju.w, cd.w, cp.w);
            avd[mt] = __builtin_bit_cast(bf16x8, cd);
            avp[mt] = __builtin_bit_cast(bf16x8, cp);
        }
#pragma unroll
        for (int nt = 0; nt < 4; nt++) {
            bf16x8 bvd = *(const bf16x8*)(w1b + nt * 8192 + (ks + 8) * 512);
            bf16x8 bvp = *(const bf16x8*)(w1b + nt * 8192 + (ks + 12) * 512);
#pragma unroll
            for (int mt = 0; mt < 4; mt++) {
                acc[mt][nt] = __builtin_amdgcn_mfma_f32_16x16x32_bf16(avd[mt], bvd, acc[mt][nt], 0, 0, 0);
                acc[mt][nt] = __builtin_amdgcn_mfma_f32_16x16x32_bf16(avp[mt], bvp, acc[mt][nt], 0, 0, 0);
            }
        }
    }

    // Hoisted: biases (needed in Phases C/E).
    float b1v[4];
#pragma unroll
    for (int nt = 0; nt < 4; nt++) b1v[nt] = b1[nb + nt * 16 + lrow];
    float b2v[2];
#pragma unroll
    for (int nt = 0; nt < 2; nt++) b2v[nt] = b2[nb2 + nt * 16 + lrow];

    // ---------------- Phase C: relu+bias -> x1 bf16 (overlay sH) ----------------
    __syncthreads();               // all layer-1 reads of sH done
    unsigned short* sx1 = sH;      // [64][268], cols 0..255
#pragma unroll
    for (int mt = 0; mt < 4; mt++)
#pragma unroll
        for (int nt = 0; nt < 4; nt++)
#pragma unroll
            for (int i = 0; i < 4; i++) {
                int row = mt * 16 + quad * 4 + i;    // C/D: row = quad*4 + reg
                int col = nb + nt * 16 + lrow;       //      col = lane&15
                float v = acc[mt][nt][i] + b1v[nt];
                v = v > 0.f ? v : 0.f;
                sx1[row * 268 + col] = cvt1(v);
            }
    __syncthreads();               // x1 complete

    // ---------------- Phase D: layer 2 (M=64, N=128, K=256) ----------------
    f32x4 acc2[4][2];
#pragma unroll
    for (int mt = 0; mt < 4; mt++)
#pragma unroll
        for (int nt = 0; nt < 2; nt++)
            acc2[mt][nt] = (f32x4){0.f, 0.f, 0.f, 0.f};

#pragma unroll 1
    for (int ks = 0; ks < 8; ks++) {
        bf16x8 bv2[2], av2[4];
#pragma unroll
        for (int nt = 0; nt < 2; nt++) bv2[nt] = *(const bf16x8*)(w2b + nt * 4096 + ks * 512);
#pragma unroll
        for (int mt = 0; mt < 4; mt++) av2[mt] = *(const bf16x8*)(sx1 + aoff[mt] + ks * 32);
#pragma unroll
        for (int mt = 0; mt < 4; mt++)
#pragma unroll
            for (int nt = 0; nt < 2; nt++)
                acc2[mt][nt] = __builtin_amdgcn_mfma_f32_16x16x32_bf16(av2[mt], bv2[nt], acc2[mt][nt], 0, 0, 0);
    }

    // ---------------- Phase E: relu+bias -> x2 bf16 (overlay) ----------------
    __syncthreads();               // all layer-2 reads of x1 done
    unsigned short* sx2 = sH;      // [64][140] (70 dw stride, gcd 2 -> free)
#pragma unroll
    for (int mt = 0; mt < 4; mt++)
#pragma unroll
        for (int nt = 0; nt < 2; nt++)
#pragma unroll
            for (int i = 0; i < 4; i++) {
                int row = mt * 16 + quad * 4 + i;
                int col = nb2 + nt * 16 + lrow;
                float v = acc2[mt][nt][i] + b2v[nt];
                v = v > 0.f ? v : 0.f;
                sx2[row * 140 + col] = cvt1(v);
            }
    __syncthreads();

    // ---------------- Phase F: layer 3 (N=2), half-dots + shfl ----------------
    {
        int r = t >> 2;            // edge row 0..63
        int c = t & 1;             // class
        int h = (t >> 1) & 1;      // K-half
        const unsigned short* xr = sx2 + r * 140 + h * 64;
        const float* w3c = sW3 + c * 128 + h * 64;
        float s = 0.f;
#pragma unroll
        for (int j = 0; j < 8; j++) {
            uint4 v = *(const uint4*)(xr + j * 8);
            f32x4 w0 = *(const f32x4*)(w3c + j * 8);
            f32x4 w1 = *(const f32x4*)(w3c + j * 8 + 4);
            s += bflo(v.x) * w0[0] + bfhi(v.x) * w0[1]
               + bflo(v.y) * w0[2] + bfhi(v.y) * w0[3]
               + bflo(v.z) * w1[0] + bfhi(v.z) * w1[1]
               + bflo(v.w) * w1[2] + bfhi(v.w) * w1[3];
        }
        s += __shfl_xor(s, 2);     // combine K-halves
        int e = e0 + r;
        if (h == 0 && e < E) out[e * 2 + c] = s + b3[c];
    }
}

extern "C" void kernel_launch(void* const* d_in, const int* in_sizes, int n_in,
                              void* d_out, int out_size, void* d_ws, size_t ws_size,
                              hipStream_t stream) {
    const float* node = (const float*)d_in[0];
    const int* src    = (const int*)d_in[1];
    const int* dst    = (const int*)d_in[2];
    const float* W1   = (const float*)d_in[3];
    const float* b1   = (const float*)d_in[4];
    const float* W2   = (const float*)d_in[5];
    const float* b2   = (const float*)d_in[6];
    const float* W3   = (const float*)d_in[7];
    const float* b3   = (const float*)d_in[8];
    float* out = (float*)d_out;
    const int NN = in_sizes[0] / H;                    // 50000 nodes
    const int E = in_sizes[1];

    unsigned short* W1P = (unsigned short*)d_ws;       // packed W1, 256 KiB
    unsigned short* W2P = W1P + 512 * 256;             // packed W2, 64 KiB
    unsigned short* NBF = W2P + 256 * 128;             // [N][128] bf16, 12.8 MB

    hipLaunchKernelGGL(prep_node, dim3((NN * H / 4 + 255) / 256), dim3(256), 0, stream, node, NBF);
    hipLaunchKernelGGL(prep_w1, dim3(512), dim3(256), 0, stream, W1, W1P);
    hipLaunchKernelGGL(prep_w2, dim3(128), dim3(256), 0, stream, W2, W2P);
    const int nblk = (E + 63) / 64;
    hipLaunchKernelGGL(fused_mlp, dim3(nblk), dim3(256), 0, stream,
                       NBF, src, dst, W1P, b1, W2P, b2, W3, b3, out, E);
}

// Round 20
// 336.967 us; speedup vs baseline: 1.8655x; 1.0359x over previous
//
#include <hip/hip_runtime.h>

// EntityLinker fused edge-MLP for MI355X (gfx950).
// Round 32: continue the VALU-trim program (the only lever that moves).
//   R31 measured: fused K-half-2 = 310.7 -> 290.1us (-6.7%, beat the
//   prediction); VALUBusy 44.6 -> 36.0. Structural levers all dead
//   (R13 pipelining null, R18/R28 staging tradeoff settled, R19 M=128
//   regressed, R30 M-split regressed). Remaining safe trims:
//   1) comb2: drop explicit fabsf, fold abs into v_cvt_pk_bf16_f32 via
//      |.| input modifiers (VOP3 float op, legal). -128 VALU/thread.
//   2) Phase C: pair i={0,1},{2,3} through v_cvt_pk_bf16_f32 + lo/hi
//      split b16 stores (rows adjacent). 16 -> 12 VALU per (mt,nt),
//      -64/thread.  3) Phase E same, -32/thread.
//   Total ~-224 VALU/thread (~12%). RNE rounding on these paths
//   (<=1ulp bf16; threshold 0.0513, R31 absmax 0.0156).
//   Predict: dur 282-288; VALUBusy ~32; flat => VALU exhausted, declare
//   plateau next round; regression => revert to R31.
//   Keeps (R31): 4 blocks/CU, N-split waves, fused K-half-2, on-the-fly
//   comb, bf16 node cache, fragment-major packed weights, vectorized sW3.

#define H 128

typedef __bf16 bf16x8 __attribute__((ext_vector_type(8)));
typedef float f32x4 __attribute__((ext_vector_type(4)));

__device__ __forceinline__ unsigned short f2bf(float f) {
    unsigned u = __builtin_bit_cast(unsigned, f);
    u += 0x7FFFu + ((u >> 16) & 1u);   // RNE
    return (unsigned short)(u >> 16);
}
__device__ __forceinline__ float bfhi(unsigned u) {
    return __builtin_bit_cast(float, u & 0xffff0000u);
}
__device__ __forceinline__ float bflo(unsigned u) {
    return __builtin_bit_cast(float, u << 16);
}
// Shared-extract diff+prod: 4 extracts + 2 sub + 2 mul + 2 cvt_pk (abs
// folded into cvt_pk input modifiers) = 10 ops for 2 diff + 2 prod bf16.
__device__ __forceinline__ void comb2(unsigned ua, unsigned ub,
                                      unsigned& dd, unsigned& pp) {
    float a0 = bflo(ua), a1 = bfhi(ua);
    float b0 = bflo(ub), b1 = bfhi(ub);
    float d0 = a0 - b0, d1 = a1 - b1;
    float p0 = a0 * b0, p1 = a1 * b1;
    unsigned rd, rp;
    asm("v_cvt_pk_bf16_f32 %0, |%1|, |%2|" : "=v"(rd) : "v"(d0), "v"(d1));
    asm("v_cvt_pk_bf16_f32 %0, %1, %2" : "=v"(rp) : "v"(p0), "v"(p1));
    dd = rd; pp = rp;
}
// Pack two f32 to bf16 pair (RNE), for epilogues.
__device__ __forceinline__ unsigned pkbf(float v0, float v1) {
    unsigned r;
    asm("v_cvt_pk_bf16_f32 %0, %1, %2" : "=v"(r) : "v"(v0), "v"(v1));
    return r;
}

__global__ void prep_node(const float* __restrict__ node, unsigned short* __restrict__ nbf) {
    int idx = blockIdx.x * 256 + threadIdx.x;      // N*H/4 threads, 4 elems each
    const f32x4* p = (const f32x4*)(node) + idx;
    f32x4 v = *p;
    ushort4 w;
    w.x = f2bf(v.x); w.y = f2bf(v.y); w.z = f2bf(v.z); w.w = f2bf(v.w);
    *(ushort4*)(nbf + idx * 4) = w;
}

// Fragment-major pack of W1 [512][256] (in,out):
//   W1P[o], o = (g_nt*16 + ks)*512 + lane*8 + j
//   row = g_nt*16 + (lane&15), k = ks*32 + (lane>>4)*8 + j
__global__ void prep_w1(const float* __restrict__ W1, unsigned short* __restrict__ W1P) {
    int o = blockIdx.x * 256 + threadIdx.x;        // 131072
    int chunk = o >> 9;
    int g_nt = chunk >> 4;
    int ks = chunk & 15;
    int r = o & 511;
    int lane = r >> 3;
    int j = r & 7;
    int row = g_nt * 16 + (lane & 15);
    int k = ks * 32 + (lane >> 4) * 8 + j;
    W1P[o] = f2bf(W1[k * 256 + row]);
}

// Fragment-major pack of W2 [256][128]:
//   W2P[o], o = (g_nt*8 + ks)*512 + lane*8 + j
__global__ void prep_w2(const float* __restrict__ W2, unsigned short* __restrict__ W2P) {
    int o = blockIdx.x * 256 + threadIdx.x;        // 32768
    int chunk = o >> 9;
    int g_nt = chunk >> 3;
    int ks = chunk & 7;
    int r = o & 511;
    int lane = r >> 3;
    int j = r & 7;
    int row = g_nt * 16 + (lane & 15);
    int k = ks * 32 + (lane >> 4) * 8 + j;
    W2P[o] = f2bf(W2[k * 128 + row]);
}

__launch_bounds__(256, 4)
__global__ void fused_mlp(const unsigned short* __restrict__ nbf,   // [N][128] bf16
                          const int* __restrict__ src,
                          const int* __restrict__ dst,
                          const unsigned short* __restrict__ W1P,  // packed
                          const float* __restrict__ b1,
                          const unsigned short* __restrict__ W2P,  // packed
                          const float* __restrict__ b2,
                          const float* __restrict__ W3,            // [128][2] f32
                          const float* __restrict__ b3,
                          float* __restrict__ out,                 // [E][2] f32
                          int E) {
    // sH: [64][268] bf16. Region P (cols 0..127): hi (never overwritten
    //     during layer 1). Region Q (cols 136..263): hj.
    // Overlays: x1 [64][268] cols 0..255 (after barrier); x2 [64][140].
    __shared__ __align__(16) unsigned short sH[64 * 268];    // 34304 B
    __shared__ __align__(16) float sW3[256];                 // [c][128]

    const int t = threadIdx.x;
    const int e0 = blockIdx.x * 64;

    const int lane = t & 63;
    const int wv = t >> 6;
    const int quad = lane >> 4;
    const int lrow = lane & 15;
    const int nb = wv * 64;        // layer-1 N-slice
    const int nb2 = wv * 32;       // layer-2 N-slice

    // Weight stream bases (N-split: each wave streams ONLY its N-slices).
    const unsigned short* w1b = W1P + wv * 32768 + lane * 8;   // wv*4*16*512
    const unsigned short* w2b = W2P + wv * 8192 + lane * 8;    // wv*2*8*512

    // ---------------- Phase A: gather hi/hj (bf16) -> LDS, line-granular --------
    {
        int r = t >> 2;            // edge row 0..63
        int q = t & 3;             // 32-col quarter (64 B = one cache line)
        int e = e0 + r;
        int ec = e < E ? e : (E - 1);
        const unsigned short* hi = nbf + (long)src[ec] * H + q * 32;
        const unsigned short* hj = nbf + (long)dst[ec] * H + q * 32;
        unsigned short* rowp = sH + r * 268 + q * 32;
#pragma unroll
        for (int b = 0; b < 4; b++) {
            uint4 a = *(const uint4*)(hi + b * 8);
            uint4 c = *(const uint4*)(hj + b * 8);
            *(uint4*)(rowp + b * 8)       = a;
            *(uint4*)(rowp + 136 + b * 8) = c;
        }
        sW3[(t & 1) * 128 + (t >> 1)] = W3[t];   // [k][c] -> [c][k]
    }
    __syncthreads();               // hi/hj visible

    // ---------------- Phase B: layer 1 (M=64, N=256, K=512), barrier-free -------
    f32x4 acc[4][4];
#pragma unroll
    for (int mt = 0; mt < 4; mt++)
#pragma unroll
        for (int nt = 0; nt < 4; nt++)
            acc[mt][nt] = (f32x4){0.f, 0.f, 0.f, 0.f};

    int aoff[4];
#pragma unroll
    for (int mt = 0; mt < 4; mt++) aoff[mt] = (mt * 16 + lrow) * 268 + quad * 8;

    // K-half 1: k 0..255  (A = hi | hj, as stored)
#pragma unroll 1
    for (int ks = 0; ks < 8; ks++) {
        const int ao = (ks < 4) ? ks * 32 : 136 + (ks - 4) * 32;
        bf16x8 bv[4], av[4];
#pragma unroll
        for (int nt = 0; nt < 4; nt++) bv[nt] = *(const bf16x8*)(w1b + nt * 8192 + ks * 512);
#pragma unroll
        for (int mt = 0; mt < 4; mt++) av[mt] = *(const bf16x8*)(sH + aoff[mt] + ao);
#pragma unroll
        for (int mt = 0; mt < 4; mt++)
#pragma unroll
            for (int nt = 0; nt < 4; nt++)
                acc[mt][nt] = __builtin_amdgcn_mfma_f32_16x16x32_bf16(av[mt], bv[nt], acc[mt][nt], 0, 0, 0);
    }

    // K-half 2 (fused): per ks, build diff (k-slice ks+8) AND prod (ks+12)
    // A-fragments from ONE hu/ju read with shared extracts, then MFMA both.
#pragma unroll 1
    for (int ks = 0; ks < 4; ks++) {
        bf16x8 avd[4], avp[4];
#pragma unroll
        for (int mt = 0; mt < 4; mt++) {
            uint4 hu = *(const uint4*)(sH + aoff[mt] + ks * 32);
            uint4 ju = *(const uint4*)(sH + aoff[mt] + 136 + ks * 32);
            uint4 cd, cp;
            comb2(hu.x, ju.x, cd.x, cp.x);
            comb2(hu.y, ju.y, cd.y, cp.y);
            comb2(hu.z, ju.z, cd.z, cp.z);
            comb2(hu.w, ju.w, cd.w, cp.w);
            avd[mt] = __builtin_bit_cast(bf16x8, cd);
            avp[mt] = __builtin_bit_cast(bf16x8, cp);
        }
#pragma unroll
        for (int nt = 0; nt < 4; nt++) {
            bf16x8 bvd = *(const bf16x8*)(w1b + nt * 8192 + (ks + 8) * 512);
            bf16x8 bvp = *(const bf16x8*)(w1b + nt * 8192 + (ks + 12) * 512);
#pragma unroll
            for (int mt = 0; mt < 4; mt++) {
                acc[mt][nt] = __builtin_amdgcn_mfma_f32_16x16x32_bf16(avd[mt], bvd, acc[mt][nt], 0, 0, 0);
                acc[mt][nt] = __builtin_amdgcn_mfma_f32_16x16x32_bf16(avp[mt], bvp, acc[mt][nt], 0, 0, 0);
            }
        }
    }

    // Hoisted: biases (needed in Phases C/E).
    float b1v[4];
#pragma unroll
    for (int nt = 0; nt < 4; nt++) b1v[nt] = b1[nb + nt * 16 + lrow];
    float b2v[2];
#pragma unroll
    for (int nt = 0; nt < 2; nt++) b2v[nt] = b2[nb2 + nt * 16 + lrow];

    // ---------------- Phase C: relu+bias -> x1 bf16 (overlay sH) ----------------
    __syncthreads();               // all layer-1 reads of sH done
    unsigned short* sx1 = sH;      // [64][268], cols 0..255
#pragma unroll
    for (int mt = 0; mt < 4; mt++)
#pragma unroll
        for (int nt = 0; nt < 4; nt++) {
            float v0 = acc[mt][nt][0] + b1v[nt]; v0 = v0 > 0.f ? v0 : 0.f;
            float v1 = acc[mt][nt][1] + b1v[nt]; v1 = v1 > 0.f ? v1 : 0.f;
            float v2 = acc[mt][nt][2] + b1v[nt]; v2 = v2 > 0.f ? v2 : 0.f;
            float v3 = acc[mt][nt][3] + b1v[nt]; v3 = v3 > 0.f ? v3 : 0.f;
            unsigned r01 = pkbf(v0, v1);
            unsigned r23 = pkbf(v2, v3);
            unsigned short* base = sx1 + (mt * 16 + quad * 4) * 268 + nb + nt * 16 + lrow;
            base[0]   = (unsigned short)r01;         // row quad*4+0
            base[268] = (unsigned short)(r01 >> 16); // row quad*4+1
            base[536] = (unsigned short)r23;         // row quad*4+2
            base[804] = (unsigned short)(r23 >> 16); // row quad*4+3
        }
    __syncthreads();               // x1 complete

    // ---------------- Phase D: layer 2 (M=64, N=128, K=256) ----------------
    f32x4 acc2[4][2];
#pragma unroll
    for (int mt = 0; mt < 4; mt++)
#pragma unroll
        for (int nt = 0; nt < 2; nt++)
            acc2[mt][nt] = (f32x4){0.f, 0.f, 0.f, 0.f};

#pragma unroll 1
    for (int ks = 0; ks < 8; ks++) {
        bf16x8 bv2[2], av2[4];
#pragma unroll
        for (int nt = 0; nt < 2; nt++) bv2[nt] = *(const bf16x8*)(w2b + nt * 4096 + ks * 512);
#pragma unroll
        for (int mt = 0; mt < 4; mt++) av2[mt] = *(const bf16x8*)(sx1 + aoff[mt] + ks * 32);
#pragma unroll
        for (int mt = 0; mt < 4; mt++)
#pragma unroll
            for (int nt = 0; nt < 2; nt++)
                acc2[mt][nt] = __builtin_amdgcn_mfma_f32_16x16x32_bf16(av2[mt], bv2[nt], acc2[mt][nt], 0, 0, 0);
    }

    // ---------------- Phase E: relu+bias -> x2 bf16 (overlay) ----------------
    __syncthreads();               // all layer-2 reads of x1 done
    unsigned short* sx2 = sH;      // [64][140] (70 dw stride, gcd 2 -> free)
#pragma unroll
    for (int mt = 0; mt < 4; mt++)
#pragma unroll
        for (int nt = 0; nt < 2; nt++) {
            float v0 = acc2[mt][nt][0] + b2v[nt]; v0 = v0 > 0.f ? v0 : 0.f;
            float v1 = acc2[mt][nt][1] + b2v[nt]; v1 = v1 > 0.f ? v1 : 0.f;
            float v2 = acc2[mt][nt][2] + b2v[nt]; v2 = v2 > 0.f ? v2 : 0.f;
            float v3 = acc2[mt][nt][3] + b2v[nt]; v3 = v3 > 0.f ? v3 : 0.f;
            unsigned r01 = pkbf(v0, v1);
            unsigned r23 = pkbf(v2, v3);
            unsigned short* base = sx2 + (mt * 16 + quad * 4) * 140 + nb2 + nt * 16 + lrow;
            base[0]   = (unsigned short)r01;
            base[140] = (unsigned short)(r01 >> 16);
            base[280] = (unsigned short)r23;
            base[420] = (unsigned short)(r23 >> 16);
        }
    __syncthreads();

    // ---------------- Phase F: layer 3 (N=2), half-dots + shfl ----------------
    {
        int r = t >> 2;            // edge row 0..63
        int c = t & 1;             // class
        int h = (t >> 1) & 1;      // K-half
        const unsigned short* xr = sx2 + r * 140 + h * 64;
        const float* w3c = sW3 + c * 128 + h * 64;
        float s = 0.f;
#pragma unroll
        for (int j = 0; j < 8; j++) {
            uint4 v = *(const uint4*)(xr + j * 8);
            f32x4 w0 = *(const f32x4*)(w3c + j * 8);
            f32x4 w1 = *(const f32x4*)(w3c + j * 8 + 4);
            s += bflo(v.x) * w0[0] + bfhi(v.x) * w0[1]
               + bflo(v.y) * w0[2] + bfhi(v.y) * w0[3]
               + bflo(v.z) * w1[0] + bfhi(v.z) * w1[1]
               + bflo(v.w) * w1[2] + bfhi(v.w) * w1[3];
        }
        s += __shfl_xor(s, 2);     // combine K-halves
        int e = e0 + r;
        if (h == 0 && e < E) out[e * 2 + c] = s + b3[c];
    }
}

extern "C" void kernel_launch(void* const* d_in, const int* in_sizes, int n_in,
                              void* d_out, int out_size, void* d_ws, size_t ws_size,
                              hipStream_t stream) {
    const float* node = (const float*)d_in[0];
    const int* src    = (const int*)d_in[1];
    const int* dst    = (const int*)d_in[2];
    const float* W1   = (const float*)d_in[3];
    const float* b1   = (const float*)d_in[4];
    const float* W2   = (const float*)d_in[5];
    const float* b2   = (const float*)d_in[6];
    const float* W3   = (const float*)d_in[7];
    const float* b3   = (const float*)d_in[8];
    float* out = (float*)d_out;
    const int NN = in_sizes[0] / H;                    // 50000 nodes
    const int E = in_sizes[1];

    unsigned short* W1P = (unsigned short*)d_ws;       // packed W1, 256 KiB
    unsigned short* W2P = W1P + 512 * 256;             // packed W2, 64 KiB
    unsigned short* NBF = W2P + 256 * 128;             // [N][128] bf16, 12.8 MB

    hipLaunchKernelGGL(prep_node, dim3((NN * H / 4 + 255) / 256), dim3(256), 0, stream, node, NBF);
    hipLaunchKernelGGL(prep_w1, dim3(512), dim3(256), 0, stream, W1, W1P);
    hipLaunchKernelGGL(prep_w2, dim3(128), dim3(256), 0, stream, W2, W2P);
    const int nblk = (E + 63) / 64;
    hipLaunchKernelGGL(fused_mlp, dim3(nblk), dim3(256), 0, stream,
                       NBF, src, dst, W1P, b1, W2P, b2, W3, b3, out, E);
}